// Round 4
// baseline (14503.076 us; speedup 1.0000x reference)
//
#include <hip/hip_runtime.h>
#include <stdint.h>

#define TT 12
#define NITERS 10
#define NCAND 1000
#define AD 6
#define BD 16
#define HD 200
#define ZD 30
#define NROWS 16000
#define NELEM 1152000u

// ws layout (float offsets).
#define OFF_WALL 0u           // [240][256] stacked [Wb;Ws;Wa] padded
#define OFF_BB   61440u       // [256]
#define OFF_WZ   61696u       // [200][32]
#define OFF_BZ   68096u       // [32]
#define OFF_WR   68128u       // [240] (padded 0 beyond 230)
#define OFF_MEAN 68368u       // [12][16][8]
#define OFF_STD  69904u       // [12][16][8]
#define OFF_ACT  3783952u     // [12][16000][8]
#define OFF_RET  5319952u     // [16000]
#define OFF_TOPK 5335952u     // int [16][100]

// ---------------- threefry2x32 (JAX-exact) ----------------
__host__ __device__ __forceinline__ uint32_t tf_rotl(uint32_t x, int r) {
  return (x << r) | (x >> (32 - r));
}
__host__ __device__ __forceinline__ void tf2x32(uint32_t k0, uint32_t k1,
                                                uint32_t& x0, uint32_t& x1) {
  uint32_t k2 = k0 ^ k1 ^ 0x1BD11BDAu;
  x0 += k0; x1 += k1;
  x0 += x1; x1 = tf_rotl(x1, 13); x1 ^= x0;
  x0 += x1; x1 = tf_rotl(x1, 15); x1 ^= x0;
  x0 += x1; x1 = tf_rotl(x1, 26); x1 ^= x0;
  x0 += x1; x1 = tf_rotl(x1,  6); x1 ^= x0;
  x0 += k1; x1 += k2 + 1u;
  x0 += x1; x1 = tf_rotl(x1, 17); x1 ^= x0;
  x0 += x1; x1 = tf_rotl(x1, 29); x1 ^= x0;
  x0 += x1; x1 = tf_rotl(x1, 16); x1 ^= x0;
  x0 += x1; x1 = tf_rotl(x1, 24); x1 ^= x0;
  x0 += k2; x1 += k0 + 2u;
  x0 += x1; x1 = tf_rotl(x1, 13); x1 ^= x0;
  x0 += x1; x1 = tf_rotl(x1, 15); x1 ^= x0;
  x0 += x1; x1 = tf_rotl(x1, 26); x1 ^= x0;
  x0 += x1; x1 = tf_rotl(x1,  6); x1 ^= x0;
  x0 += k0; x1 += k1 + 3u;
  x0 += x1; x1 = tf_rotl(x1, 17); x1 ^= x0;
  x0 += x1; x1 = tf_rotl(x1, 29); x1 ^= x0;
  x0 += x1; x1 = tf_rotl(x1, 16); x1 ^= x0;
  x0 += x1; x1 = tf_rotl(x1, 24); x1 ^= x0;
  x0 += k1; x1 += k2 + 4u;
  x0 += x1; x1 = tf_rotl(x1, 13); x1 ^= x0;
  x0 += x1; x1 = tf_rotl(x1, 15); x1 ^= x0;
  x0 += x1; x1 = tf_rotl(x1, 26); x1 ^= x0;
  x0 += x1; x1 = tf_rotl(x1,  6); x1 ^= x0;
  x0 += k2; x1 += k0 + 5u;
}

__device__ __forceinline__ float bits_to_normal(uint32_t bits) {
  uint32_t fb = (bits >> 9) | 0x3F800000u;
  float f = __uint_as_float(fb) - 1.0f;          // [0,1)
  float u = f * 2.0f - 0.99999994f;              // scale==2.0f exactly
  u = fmaxf(-0.99999994f, u);
  float w = -log1pf(-u * u);
  float p;
  if (w < 5.0f) {
    w = w - 2.5f;
    p = 2.81022636e-08f;
    p = fmaf(p, w, 3.43273939e-07f);
    p = fmaf(p, w, -3.5233877e-06f);
    p = fmaf(p, w, -4.39150654e-06f);
    p = fmaf(p, w, 0.00021858087f);
    p = fmaf(p, w, -0.00125372503f);
    p = fmaf(p, w, -0.00417768164f);
    p = fmaf(p, w, 0.246640727f);
    p = fmaf(p, w, 1.50140941f);
  } else {
    w = sqrtf(w) - 3.0f;
    p = -0.000200214257f;
    p = fmaf(p, w, 0.000100950558f);
    p = fmaf(p, w, 0.00134934322f);
    p = fmaf(p, w, -0.00367342844f);
    p = fmaf(p, w, 0.00573950773f);
    p = fmaf(p, w, -0.0076224613f);
    p = fmaf(p, w, 0.00943887047f);
    p = fmaf(p, w, 1.00167406f);
    p = fmaf(p, w, 2.83297682f);
  }
  return 1.41421354f * (p * u);
}

// ---------------- prep: pack weights, init mean/std ----------------
__global__ __launch_bounds__(256) void k_prep(const float* Wb, const float* Ws_,
                                              const float* Wa, const float* bb,
                                              const float* Wz, const float* bz,
                                              const float* Wr, float* ws) {
  int i = blockIdx.x * 256 + threadIdx.x;
  if (i < 61440) {
    int k = i >> 8, c = i & 255;
    float v = 0.f;
    if (c < HD) {
      if (k < 200)      v = Wb[k * HD + c];
      else if (k < 230) v = Ws_[(k - 200) * HD + c];
      else if (k < 236) v = Wa[(k - 230) * HD + c];
    }
    ws[OFF_WALL + i] = v;
  } else if (i < 61696) {
    int c = i - 61440;
    ws[i] = (c < HD) ? bb[c] : 0.f;
  } else if (i < 68096) {
    int j = i - 61696; int k = j >> 5, z = j & 31;
    ws[i] = (z < ZD) ? Wz[k * ZD + z] : 0.f;
  } else if (i < 68128) {
    int z = i - 68096;
    ws[i] = (z < ZD) ? bz[z] : 0.f;
  } else if (i < 68368) {
    int k = i - 68128;
    ws[i] = (k < 230) ? Wr[k] : 0.f;
  } else if (i < 69904) {
    ws[i] = 0.f;   // mean
  } else if (i < 71440) {
    ws[i] = 1.f;   // std
  }
}

// ---------------- actions = mean + std * normal(threefry) ----------------
__global__ __launch_bounds__(256) void k_actions(uint32_t k0, uint32_t k1, float* ws) {
  uint32_t idx = blockIdx.x * 256u + threadIdx.x;
  if (idx >= NELEM) return;
  uint32_t x0 = 0u, x1 = idx;
  tf2x32(k0, k1, x0, x1);
  float z = bits_to_normal(x0 ^ x1);
  uint32_t a = idx % 6u;  uint32_t q = idx / 6u;
  uint32_t c = q % 1000u; uint32_t q2 = q / 1000u;
  uint32_t b = q2 % 16u;  uint32_t t = q2 / 16u;
  uint32_t mi = (t * 16u + b) * 8u + a;
  float m = ws[OFF_MEAN + mi];
  float s = ws[OFF_STD + mi];
  ws[OFF_ACT + ((size_t)t * NROWS + b * 1000u + c) * 8u + a] = fmaf(s, z, m);
}

// ---------------- full 12-step rollout, barrier-free waves ----------------
// 16 rows/block, 4 rows/wave; each wave fully owns its rows end-to-end.
// stage1: h = tanh([b|s|a_t] @ W_all + bb)   (K=236, N=200)
// stage2: lanes (rh,z): s_new = tanh(h @ Wz + bz); rewards in registers.
__global__ __launch_bounds__(256, 2) void k_roll(float* __restrict__ ws,
                                                 const float* __restrict__ belief,
                                                 const float* __restrict__ state,
                                                 const float* __restrict__ br) {
  __shared__ float xls[16][204];       // b_cur / b_new (per-wave-private rows)
  __shared__ float sls[16][32];        // s_cur / s_new

  const int tid = threadIdx.x;
  const int wv = tid >> 6;
  const int ln = tid & 63;
  const int c0 = ln * 4;
  const bool colok = (c0 < HD);
  const int row0g = blockIdx.x * 16;
  const int lr0 = wv * 4;              // wave's local row base
  const int grow0 = row0g + lr0;       // wave's global row base

  const float* __restrict__ Wall = ws + OFF_WALL;
  const float* __restrict__ Wzg  = ws + OFF_WZ;
  const float* __restrict__ Wrp  = ws + OFF_WR;

  // persistent per-lane constants
  float bbv[4];
  *(float4*)bbv = *(const float4*)(ws + OFF_BB + c0);
  float wr4[4] = {0.f, 0.f, 0.f, 0.f};
  if (colok) *(float4*)wr4 = *(const float4*)(Wrp + c0);
  const int z = ln & 31;
  const int rh = ln >> 5;              // 0: rows lr0+0/1, 1: rows lr0+2/3
  const float bz_z = ws[OFF_BZ + z];
  const float wrz  = Wrp[200 + z];     // 0 for z>=30 (padded)
  const float br0 = br[0];

  // init own rows (no barrier needed: per-wave-private LDS rows)
#pragma unroll
  for (int r = 0; r < 4; ++r) {
    const int b = (grow0 + r) / 1000;
    for (int c = ln; c < HD; c += 64)
      xls[lr0 + r][c] = belief[(size_t)b * HD + c];
    if (ln < 32) sls[lr0 + r][ln] = (ln < ZD) ? state[(size_t)b * ZD + ln] : 0.f;
  }
  float ret[4] = {0.f, 0.f, 0.f, 0.f};

  for (int t = 0; t < TT; ++t) {
    const float* __restrict__ actp =
        ws + OFF_ACT + ((size_t)t * NROWS + grow0) * 8;

    float acc[4][4];
#pragma unroll
    for (int r = 0; r < 4; ++r) {
      acc[r][0] = bbv[0]; acc[r][1] = bbv[1]; acc[r][2] = bbv[2]; acc[r][3] = bbv[3];
    }

    // ---- region A: k in [0,200) from xls (broadcast b128) ----
    for (int k = 0; k < 200; k += 4) {
      float xv[4][4];
#pragma unroll
      for (int r = 0; r < 4; ++r)
        *(float4*)xv[r] = *(const float4*)&xls[lr0 + r][k];
#pragma unroll
      for (int i = 0; i < 4; ++i) {
        float wv4[4];
        *(float4*)wv4 = *(const float4*)(Wall + (size_t)(k + i) * 256 + c0);
#pragma unroll
        for (int r = 0; r < 4; ++r) {
          const float xs = xv[r][i];
          acc[r][0] = fmaf(xs, wv4[0], acc[r][0]);
          acc[r][1] = fmaf(xs, wv4[1], acc[r][1]);
          acc[r][2] = fmaf(xs, wv4[2], acc[r][2]);
          acc[r][3] = fmaf(xs, wv4[3], acc[r][3]);
        }
      }
    }
    // ---- region B: k in [200,230) from sls ----
#pragma unroll
    for (int kb = 0; kb < 28; kb += 4) {
      float xv[4][4];
#pragma unroll
      for (int r = 0; r < 4; ++r)
        *(float4*)xv[r] = *(const float4*)&sls[lr0 + r][kb];
#pragma unroll
      for (int i = 0; i < 4; ++i) {
        float wv4[4];
        *(float4*)wv4 = *(const float4*)(Wall + (size_t)(200 + kb + i) * 256 + c0);
#pragma unroll
        for (int r = 0; r < 4; ++r) {
          const float xs = xv[r][i];
          acc[r][0] = fmaf(xs, wv4[0], acc[r][0]);
          acc[r][1] = fmaf(xs, wv4[1], acc[r][1]);
          acc[r][2] = fmaf(xs, wv4[2], acc[r][2]);
          acc[r][3] = fmaf(xs, wv4[3], acc[r][3]);
        }
      }
    }
    {
      float xv[4][2];
#pragma unroll
      for (int r = 0; r < 4; ++r)
        *(float2*)xv[r] = *(const float2*)&sls[lr0 + r][28];
#pragma unroll
      for (int i = 0; i < 2; ++i) {
        float wv4[4];
        *(float4*)wv4 = *(const float4*)(Wall + (size_t)(228 + i) * 256 + c0);
#pragma unroll
        for (int r = 0; r < 4; ++r) {
          const float xs = xv[r][i];
          acc[r][0] = fmaf(xs, wv4[0], acc[r][0]);
          acc[r][1] = fmaf(xs, wv4[1], acc[r][1]);
          acc[r][2] = fmaf(xs, wv4[2], acc[r][2]);
          acc[r][3] = fmaf(xs, wv4[3], acc[r][3]);
        }
      }
    }
    // ---- region C: k in [230,236) from actions (wave-uniform) ----
    {
      float xa[4][4], xa2[4][2];
#pragma unroll
      for (int r = 0; r < 4; ++r) {
        *(float4*)xa[r]  = *(const float4*)(actp + (size_t)r * 8);
        *(float2*)xa2[r] = *(const float2*)(actp + (size_t)r * 8 + 4);
      }
#pragma unroll
      for (int i = 0; i < 4; ++i) {
        float wv4[4];
        *(float4*)wv4 = *(const float4*)(Wall + (size_t)(230 + i) * 256 + c0);
#pragma unroll
        for (int r = 0; r < 4; ++r) {
          const float xs = xa[r][i];
          acc[r][0] = fmaf(xs, wv4[0], acc[r][0]);
          acc[r][1] = fmaf(xs, wv4[1], acc[r][1]);
          acc[r][2] = fmaf(xs, wv4[2], acc[r][2]);
          acc[r][3] = fmaf(xs, wv4[3], acc[r][3]);
        }
      }
#pragma unroll
      for (int i = 0; i < 2; ++i) {
        float wv4[4];
        *(float4*)wv4 = *(const float4*)(Wall + (size_t)(234 + i) * 256 + c0);
#pragma unroll
        for (int r = 0; r < 4; ++r) {
          const float xs = xa2[r][i];
          acc[r][0] = fmaf(xs, wv4[0], acc[r][0]);
          acc[r][1] = fmaf(xs, wv4[1], acc[r][1]);
          acc[r][2] = fmaf(xs, wv4[2], acc[r][2]);
          acc[r][3] = fmaf(xs, wv4[3], acc[r][3]);
        }
      }
    }

    // tanh + write h to xls + per-lane reward (h . Wr) contribution
#pragma unroll
    for (int r = 0; r < 4; ++r) {
      float h[4];
      h[0] = tanhf(acc[r][0]); h[1] = tanhf(acc[r][1]);
      h[2] = tanhf(acc[r][2]); h[3] = tanhf(acc[r][3]);
      if (colok) {
        *(float4*)&xls[lr0 + r][c0] = *(float4*)h;
        ret[r] = fmaf(h[0], wr4[0], ret[r]);
        ret[r] = fmaf(h[1], wr4[1], ret[r]);
        ret[r] = fmaf(h[2], wr4[2], ret[r]);
        ret[r] = fmaf(h[3], wr4[3], ret[r]);
      }
    }
    // within-wave LDS write->read ordering is program order; no barrier.

    // ---- stage 2: lanes (rh, z); 2 rows per half-wave ----
    {
      const int r0 = lr0 + rh * 2;
      float p0 = 0.f, p1 = 0.f;
      for (int k = 0; k < 200; k += 4) {
        const float w0 = Wzg[(size_t)(k + 0) * 32 + z];
        const float w1 = Wzg[(size_t)(k + 1) * 32 + z];
        const float w2 = Wzg[(size_t)(k + 2) * 32 + z];
        const float w3 = Wzg[(size_t)(k + 3) * 32 + z];
        float xA[4], xB[4];
        *(float4*)xA = *(const float4*)&xls[r0][k];
        *(float4*)xB = *(const float4*)&xls[r0 + 1][k];
        p0 = fmaf(xA[0], w0, p0); p1 = fmaf(xB[0], w0, p1);
        p0 = fmaf(xA[1], w1, p0); p1 = fmaf(xB[1], w1, p1);
        p0 = fmaf(xA[2], w2, p0); p1 = fmaf(xB[2], w2, p1);
        p0 = fmaf(xA[3], w3, p0); p1 = fmaf(xB[3], w3, p1);
      }
      const float s0n = tanhf(p0 + bz_z);
      const float s1n = tanhf(p1 + bz_z);
      if (z < ZD) {
        sls[r0][z] = s0n;
        sls[r0 + 1][z] = s1n;
      }
      // wrz==0 for z>=30, so garbage tanh values contribute nothing
      if (rh == 0) {
        ret[0] = fmaf(s0n, wrz, ret[0]);
        ret[1] = fmaf(s1n, wrz, ret[1]);
      } else {
        ret[2] = fmaf(s0n, wrz, ret[2]);
        ret[3] = fmaf(s1n, wrz, ret[3]);
      }
    }
  }

  // final: butterfly-reduce rewards across the wave, write 4 returns
#pragma unroll
  for (int r = 0; r < 4; ++r) {
#pragma unroll
    for (int m = 1; m < 64; m <<= 1) ret[r] += __shfl_xor(ret[r], m, 64);
  }
  if (ln < 4) {
    float v = (ln == 0) ? ret[0] : (ln == 1) ? ret[1] : (ln == 2) ? ret[2] : ret[3];
    ws[OFF_RET + grow0 + ln] = v + 12.0f * br0;
  }
}

// ---------------- top-k via full bitonic sort (desc, ties by index) ----------------
__global__ __launch_bounds__(1024) void k_topk(float* ws) {
  __shared__ float sv[1024];
  __shared__ int si[1024];
  const int b = blockIdx.x, tid = threadIdx.x;
  const float* ret = ws + OFF_RET + b * 1000;
  sv[tid] = (tid < 1000) ? ret[tid] : -3.0e38f;
  si[tid] = tid;
  __syncthreads();
  for (int k = 2; k <= 1024; k <<= 1) {
    for (int j = k >> 1; j > 0; j >>= 1) {
      int ixj = tid ^ j;
      if (ixj > tid) {
        float v1 = sv[tid], v2 = sv[ixj];
        int i1 = si[tid], i2 = si[ixj];
        bool gt = (v1 < v2) || (v1 == v2 && i1 > i2);
        bool up = ((tid & k) == 0);
        if (up ? gt : !gt) {
          sv[tid] = v2; sv[ixj] = v1;
          si[tid] = i2; si[ixj] = i1;
        }
      }
      __syncthreads();
    }
  }
  int* topk = (int*)(ws + OFF_TOPK);
  if (tid < 100) topk[b * 100 + tid] = si[tid];
}

// ---------------- mean/std over elites: one wave per (t,b,a) ----------------
__global__ __launch_bounds__(256) void k_meanstd(float* ws) {
  const int g = blockIdx.x * 4 + (threadIdx.x >> 6);  // 0..1151
  const int ln = threadIdx.x & 63;
  const int t = g / 96; const int rem = g - t * 96;
  const int b = rem / 6; const int a = rem - b * 6;
  const int* topk = (const int*)(ws + OFF_TOPK) + b * 100;
  const float* act = ws + OFF_ACT + (size_t)t * NROWS * 8;
  const bool h2 = (ln < 36);
  int c1 = topk[ln];
  float x1 = act[((size_t)b * 1000 + c1) * 8 + a];
  float x2 = 0.f;
  if (h2) { int cc = topk[ln + 64]; x2 = act[((size_t)b * 1000 + cc) * 8 + a]; }
  float s = x1 + x2;
#pragma unroll
  for (int m = 1; m < 64; m <<= 1) s += __shfl_xor(s, m, 64);
  const float mean = s / 100.0f;
  float d = x1 - mean; float qq = d * d;
  if (h2) { float d2 = x2 - mean; qq += d2 * d2; }
#pragma unroll
  for (int m = 1; m < 64; m <<= 1) qq += __shfl_xor(qq, m, 64);
  if (ln == 0) {
    ws[OFF_MEAN + ((size_t)t * 16 + b) * 8 + a] = mean;
    ws[OFF_STD  + ((size_t)t * 16 + b) * 8 + a] = sqrtf(qq / 100.0f);
  }
}

__global__ void k_out(const float* ws, float* out) {
  int i = threadIdx.x;
  if (i < 96) out[i] = ws[OFF_MEAN + (i / 6) * 8 + (i % 6)];
}

extern "C" void kernel_launch(void* const* d_in, const int* in_sizes, int n_in,
                              void* d_out, int out_size, void* d_ws, size_t ws_size,
                              hipStream_t stream) {
  const float* belief = (const float*)d_in[0];
  const float* state  = (const float*)d_in[1];
  const float* Wb  = (const float*)d_in[2];
  const float* Ws_ = (const float*)d_in[3];
  const float* Wa  = (const float*)d_in[4];
  const float* bb  = (const float*)d_in[5];
  const float* Wz  = (const float*)d_in[6];
  const float* bz  = (const float*)d_in[7];
  const float* Wr  = (const float*)d_in[8];
  const float* br  = (const float*)d_in[9];
  float* ws = (float*)d_ws;   // needs ~21.4 MB

  k_prep<<<280, 256, 0, stream>>>(Wb, Ws_, Wa, bb, Wz, bz, Wr, ws);

  for (int it = 0; it < NITERS; ++it) {
    uint32_t f0 = 0u, f1 = (uint32_t)it;
    tf2x32(0u, 42u, f0, f1);
    k_actions<<<4500, 256, 0, stream>>>(f0, f1, ws);
    k_roll<<<1000, 256, 0, stream>>>(ws, belief, state, br);
    k_topk<<<16, 1024, 0, stream>>>(ws);
    k_meanstd<<<288, 256, 0, stream>>>(ws);
  }
  k_out<<<1, 128, 0, stream>>>(ws, (float*)d_out);
}

// Round 5
// 4465.661 us; speedup vs baseline: 3.2477x; 3.2477x over previous
//
#include <hip/hip_runtime.h>
#include <stdint.h>

#define TT 12
#define NITERS 10
#define NCAND 1000
#define AD 6
#define BD 16
#define HD 200
#define ZD 30
#define NROWS 16000
#define NELEM 1152000u

// ws layout (float offsets).
#define OFF_WALL 0u           // [240][256] stacked [Wb;Ws;Wa] padded (rows 236..239 = 0)
#define OFF_BB   61440u       // [256]
#define OFF_WZ   61696u       // [200][32]
#define OFF_BZ   68096u       // [32]
#define OFF_WR   68128u       // [240] (padded 0 beyond 230)
#define OFF_MEAN 68368u       // [12][16][8]
#define OFF_STD  69904u       // [12][16][8]
#define OFF_ACT  3783952u     // [12][16000][8]
#define OFF_RET  5319952u     // [16000]
#define OFF_TOPK 5335952u     // int [16][100]

// ---------------- threefry2x32 (JAX-exact) ----------------
__host__ __device__ __forceinline__ uint32_t tf_rotl(uint32_t x, int r) {
  return (x << r) | (x >> (32 - r));
}
__host__ __device__ __forceinline__ void tf2x32(uint32_t k0, uint32_t k1,
                                                uint32_t& x0, uint32_t& x1) {
  uint32_t k2 = k0 ^ k1 ^ 0x1BD11BDAu;
  x0 += k0; x1 += k1;
  x0 += x1; x1 = tf_rotl(x1, 13); x1 ^= x0;
  x0 += x1; x1 = tf_rotl(x1, 15); x1 ^= x0;
  x0 += x1; x1 = tf_rotl(x1, 26); x1 ^= x0;
  x0 += x1; x1 = tf_rotl(x1,  6); x1 ^= x0;
  x0 += k1; x1 += k2 + 1u;
  x0 += x1; x1 = tf_rotl(x1, 17); x1 ^= x0;
  x0 += x1; x1 = tf_rotl(x1, 29); x1 ^= x0;
  x0 += x1; x1 = tf_rotl(x1, 16); x1 ^= x0;
  x0 += x1; x1 = tf_rotl(x1, 24); x1 ^= x0;
  x0 += k2; x1 += k0 + 2u;
  x0 += x1; x1 = tf_rotl(x1, 13); x1 ^= x0;
  x0 += x1; x1 = tf_rotl(x1, 15); x1 ^= x0;
  x0 += x1; x1 = tf_rotl(x1, 26); x1 ^= x0;
  x0 += x1; x1 = tf_rotl(x1,  6); x1 ^= x0;
  x0 += k0; x1 += k1 + 3u;
  x0 += x1; x1 = tf_rotl(x1, 17); x1 ^= x0;
  x0 += x1; x1 = tf_rotl(x1, 29); x1 ^= x0;
  x0 += x1; x1 = tf_rotl(x1, 16); x1 ^= x0;
  x0 += x1; x1 = tf_rotl(x1, 24); x1 ^= x0;
  x0 += k1; x1 += k2 + 4u;
  x0 += x1; x1 = tf_rotl(x1, 13); x1 ^= x0;
  x0 += x1; x1 = tf_rotl(x1, 15); x1 ^= x0;
  x0 += x1; x1 = tf_rotl(x1, 26); x1 ^= x0;
  x0 += x1; x1 = tf_rotl(x1,  6); x1 ^= x0;
  x0 += k2; x1 += k0 + 5u;
}

__device__ __forceinline__ float bits_to_normal(uint32_t bits) {
  uint32_t fb = (bits >> 9) | 0x3F800000u;
  float f = __uint_as_float(fb) - 1.0f;          // [0,1)
  float u = f * 2.0f - 0.99999994f;              // scale==2.0f exactly
  u = fmaxf(-0.99999994f, u);
  float w = -log1pf(-u * u);
  float p;
  if (w < 5.0f) {
    w = w - 2.5f;
    p = 2.81022636e-08f;
    p = fmaf(p, w, 3.43273939e-07f);
    p = fmaf(p, w, -3.5233877e-06f);
    p = fmaf(p, w, -4.39150654e-06f);
    p = fmaf(p, w, 0.00021858087f);
    p = fmaf(p, w, -0.00125372503f);
    p = fmaf(p, w, -0.00417768164f);
    p = fmaf(p, w, 0.246640727f);
    p = fmaf(p, w, 1.50140941f);
  } else {
    w = sqrtf(w) - 3.0f;
    p = -0.000200214257f;
    p = fmaf(p, w, 0.000100950558f);
    p = fmaf(p, w, 0.00134934322f);
    p = fmaf(p, w, -0.00367342844f);
    p = fmaf(p, w, 0.00573950773f);
    p = fmaf(p, w, -0.0076224613f);
    p = fmaf(p, w, 0.00943887047f);
    p = fmaf(p, w, 1.00167406f);
    p = fmaf(p, w, 2.83297682f);
  }
  return 1.41421354f * (p * u);
}

// ---------------- prep: pack weights, init mean/std ----------------
__global__ __launch_bounds__(256) void k_prep(const float* Wb, const float* Ws_,
                                              const float* Wa, const float* bb,
                                              const float* Wz, const float* bz,
                                              const float* Wr, float* ws) {
  int i = blockIdx.x * 256 + threadIdx.x;
  if (i < 61440) {
    int k = i >> 8, c = i & 255;
    float v = 0.f;
    if (c < HD) {
      if (k < 200)      v = Wb[k * HD + c];
      else if (k < 230) v = Ws_[(k - 200) * HD + c];
      else if (k < 236) v = Wa[(k - 230) * HD + c];
    }
    ws[OFF_WALL + i] = v;
  } else if (i < 61696) {
    int c = i - 61440;
    ws[i] = (c < HD) ? bb[c] : 0.f;
  } else if (i < 68096) {
    int j = i - 61696; int k = j >> 5, z = j & 31;
    ws[i] = (z < ZD) ? Wz[k * ZD + z] : 0.f;
  } else if (i < 68128) {
    int z = i - 68096;
    ws[i] = (z < ZD) ? bz[z] : 0.f;
  } else if (i < 68368) {
    int k = i - 68128;
    ws[i] = (k < 230) ? Wr[k] : 0.f;
  } else if (i < 69904) {
    ws[i] = 0.f;   // mean
  } else if (i < 71440) {
    ws[i] = 1.f;   // std
  }
}

// ---------------- actions = mean + std * normal(threefry) ----------------
__global__ __launch_bounds__(256) void k_actions(uint32_t k0, uint32_t k1, float* ws) {
  uint32_t idx = blockIdx.x * 256u + threadIdx.x;
  if (idx >= NELEM) return;
  uint32_t x0 = 0u, x1 = idx;
  tf2x32(k0, k1, x0, x1);
  float z = bits_to_normal(x0 ^ x1);
  uint32_t a = idx % 6u;  uint32_t q = idx / 6u;
  uint32_t c = q % 1000u; uint32_t q2 = q / 1000u;
  uint32_t b = q2 % 16u;  uint32_t t = q2 / 16u;
  uint32_t mi = (t * 16u + b) * 8u + a;
  float m = ws[OFF_MEAN + mi];
  float s = ws[OFF_STD + mi];
  ws[OFF_ACT + ((size_t)t * NROWS + b * 1000u + c) * 8u + a] = fmaf(s, z, m);
}

// ---------------- full 12-step rollout, LDS-staged W panels ----------------
// 32 rows/block, 8 rows/wave. W_all streamed through LDS double-buffer
// (8 k-rows x 256 cols = 8KB/panel), read ONCE per block per step and
// shared by all 4 waves. x lives in unified xall[32][240] = [b|s|a|0].
// Stage-2 + rewards are wave-private (no barriers beyond W panels).
__global__ __launch_bounds__(256) void k_roll(float* __restrict__ ws,
                                              const float* __restrict__ belief,
                                              const float* __restrict__ state,
                                              const float* __restrict__ br) {
  __shared__ float Wpan[2][2048];      // 2 x (8 k-rows x 256 cols) = 16 KB
  __shared__ float xall[32][240];      // [b(0..200)|s(200..230)|a(230..236)|0] = 30 KB

  const int tid = threadIdx.x;
  const int wv = tid >> 6;
  const int ln = tid & 63;
  const int c0 = ln * 4;
  const bool colok = (c0 < HD);
  const int row0g = blockIdx.x * 32;
  const int lr0 = wv * 8;              // wave's local row base
  const int grow0 = row0g + lr0;       // wave's global row base

  const float* __restrict__ Wall = ws + OFF_WALL;
  const float* __restrict__ Wzg  = ws + OFF_WZ;
  const float* __restrict__ Wrp  = ws + OFF_WR;

  // persistent per-lane constants
  float bbv[4];
  *(float4*)bbv = *(const float4*)(ws + OFF_BB + c0);
  float wr4[4] = {0.f, 0.f, 0.f, 0.f};
  if (colok) *(float4*)wr4 = *(const float4*)(Wrp + c0);
  const int z = ln & 31;
  const int rh = ln >> 5;              // half-wave: rows lr0+rh*4 .. +4
  const float bz_z = ws[OFF_BZ + z];
  const float wrz  = Wrp[200 + z];     // 0 for z>=30 (padded)
  const float br0 = br[0];

  // init own rows of xall (wave-private; no barrier needed)
#pragma unroll
  for (int r = 0; r < 8; ++r) {
    const int b = (grow0 + r) / 1000;
    for (int c = ln; c < HD; c += 64)
      xall[lr0 + r][c] = belief[(size_t)b * HD + c];
    if (ln < 32)
      xall[lr0 + r][200 + ln] = (ln < ZD) ? state[(size_t)b * ZD + ln] : 0.f;
    else if (ln < 40)
      xall[lr0 + r][232 + (ln - 32)] = 0.f;   // zero pad 232..239
  }

  // stage panel 0 (k rows 0..8)
  {
    float4 s0 = *(const float4*)(Wall + (size_t)tid * 4);
    float4 s1 = *(const float4*)(Wall + 1024 + (size_t)tid * 4);
    *(float4*)&Wpan[0][tid * 4] = s0;
    *(float4*)&Wpan[0][1024 + tid * 4] = s1;
  }
  float ret[8] = {0.f, 0.f, 0.f, 0.f, 0.f, 0.f, 0.f, 0.f};
  __syncthreads();

  int cur = 0;
  for (int t = 0; t < TT; ++t) {
    const float* __restrict__ actp =
        ws + OFF_ACT + ((size_t)t * NROWS + grow0) * 8;

    // write this step's actions into xall[own rows][230..236)
    if (ln < 48) {
      const int r = ln / 6, c = ln - r * 6;
      xall[lr0 + r][230 + c] = actp[r * 8 + c];
    }

    float acc[8][4];
#pragma unroll
    for (int r = 0; r < 8; ++r) {
      acc[r][0] = bbv[0]; acc[r][1] = bbv[1]; acc[r][2] = bbv[2]; acc[r][3] = bbv[3];
    }

    // ---- K loop over 30 panels of 8 ks; T14 split staging of next panel ----
    for (int p = 0; p < 30; ++p) {
      const int nb = cur ^ 1;
      const int knext = (p < 29) ? (p + 1) * 8 : 0;   // wrap: next step reuses p0
      // issue next-panel global loads early (latency hides under compute)
      const float* gW = Wall + (size_t)knext * 256;
      float4 s0 = *(const float4*)(gW + (size_t)tid * 4);
      float4 s1 = *(const float4*)(gW + 1024 + (size_t)tid * 4);

      // compute current panel from LDS
      const float* Wp = &Wpan[cur][0];
#pragma unroll
      for (int kq = 0; kq < 2; ++kq) {
        const int kb = p * 8 + kq * 4;
        float xv[8][4];
#pragma unroll
        for (int r = 0; r < 8; ++r)
          *(float4*)xv[r] = *(const float4*)&xall[lr0 + r][kb];
#pragma unroll
        for (int i = 0; i < 4; ++i) {
          float wv4[4];
          *(float4*)wv4 = *(const float4*)(Wp + (kq * 4 + i) * 256 + c0);
#pragma unroll
          for (int r = 0; r < 8; ++r) {
            const float xs = xv[r][i];
            acc[r][0] = fmaf(xs, wv4[0], acc[r][0]);
            acc[r][1] = fmaf(xs, wv4[1], acc[r][1]);
            acc[r][2] = fmaf(xs, wv4[2], acc[r][2]);
            acc[r][3] = fmaf(xs, wv4[3], acc[r][3]);
          }
        }
      }

      // write staged regs into the other buffer, then block-wide handoff
      *(float4*)&Wpan[nb][tid * 4] = s0;
      *(float4*)&Wpan[nb][1024 + tid * 4] = s1;
      __syncthreads();
      cur = nb;
    }

    // ---- stage-1 epilogue: tanh, write b_new, h.Wr reward ----
#pragma unroll
    for (int r = 0; r < 8; ++r) {
      float h[4];
      h[0] = tanhf(acc[r][0]); h[1] = tanhf(acc[r][1]);
      h[2] = tanhf(acc[r][2]); h[3] = tanhf(acc[r][3]);
      if (colok) {
        *(float4*)&xall[lr0 + r][c0] = *(float4*)h;
        ret[r] = fmaf(h[0], wr4[0], ret[r]);
        ret[r] = fmaf(h[1], wr4[1], ret[r]);
        ret[r] = fmaf(h[2], wr4[2], ret[r]);
        ret[r] = fmaf(h[3], wr4[3], ret[r]);
      }
    }
    // intra-wave program order covers xall write->read; no barrier.

    // ---- stage 2: half-wave rh owns 4 rows; lane z computes s_new[z] ----
    {
      const int r0 = lr0 + rh * 4;
      float pz[4] = {0.f, 0.f, 0.f, 0.f};
      for (int k = 0; k < 200; k += 4) {
        const float w0 = Wzg[(size_t)(k + 0) * 32 + z];
        const float w1 = Wzg[(size_t)(k + 1) * 32 + z];
        const float w2 = Wzg[(size_t)(k + 2) * 32 + z];
        const float w3 = Wzg[(size_t)(k + 3) * 32 + z];
#pragma unroll
        for (int j = 0; j < 4; ++j) {
          float xA[4];
          *(float4*)xA = *(const float4*)&xall[r0 + j][k];
          pz[j] = fmaf(xA[0], w0, pz[j]);
          pz[j] = fmaf(xA[1], w1, pz[j]);
          pz[j] = fmaf(xA[2], w2, pz[j]);
          pz[j] = fmaf(xA[3], w3, pz[j]);
        }
      }
      float sn[4];
#pragma unroll
      for (int j = 0; j < 4; ++j) {
        sn[j] = tanhf(pz[j] + bz_z);
        if (z < ZD) xall[r0 + j][200 + z] = sn[j];
      }
      // wrz==0 for z>=30 -> padded lanes contribute exact 0
      if (rh == 0) {
        ret[0] = fmaf(sn[0], wrz, ret[0]);
        ret[1] = fmaf(sn[1], wrz, ret[1]);
        ret[2] = fmaf(sn[2], wrz, ret[2]);
        ret[3] = fmaf(sn[3], wrz, ret[3]);
      } else {
        ret[4] = fmaf(sn[0], wrz, ret[4]);
        ret[5] = fmaf(sn[1], wrz, ret[5]);
        ret[6] = fmaf(sn[2], wrz, ret[6]);
        ret[7] = fmaf(sn[3], wrz, ret[7]);
      }
    }
  }

  // final: butterfly-reduce rewards across the wave, write 8 returns
#pragma unroll
  for (int r = 0; r < 8; ++r) {
#pragma unroll
    for (int m = 1; m < 64; m <<= 1) ret[r] += __shfl_xor(ret[r], m, 64);
  }
  if (ln < 8) {
    float v = (ln == 0) ? ret[0] : (ln == 1) ? ret[1] : (ln == 2) ? ret[2] :
              (ln == 3) ? ret[3] : (ln == 4) ? ret[4] : (ln == 5) ? ret[5] :
              (ln == 6) ? ret[6] : ret[7];
    ws[OFF_RET + grow0 + ln] = v + 12.0f * br0;
  }
}

// ---------------- top-k via full bitonic sort (desc, ties by index) ----------------
__global__ __launch_bounds__(1024) void k_topk(float* ws) {
  __shared__ float sv[1024];
  __shared__ int si[1024];
  const int b = blockIdx.x, tid = threadIdx.x;
  const float* ret = ws + OFF_RET + b * 1000;
  sv[tid] = (tid < 1000) ? ret[tid] : -3.0e38f;
  si[tid] = tid;
  __syncthreads();
  for (int k = 2; k <= 1024; k <<= 1) {
    for (int j = k >> 1; j > 0; j >>= 1) {
      int ixj = tid ^ j;
      if (ixj > tid) {
        float v1 = sv[tid], v2 = sv[ixj];
        int i1 = si[tid], i2 = si[ixj];
        bool gt = (v1 < v2) || (v1 == v2 && i1 > i2);
        bool up = ((tid & k) == 0);
        if (up ? gt : !gt) {
          sv[tid] = v2; sv[ixj] = v1;
          si[tid] = i2; si[ixj] = i1;
        }
      }
      __syncthreads();
    }
  }
  int* topk = (int*)(ws + OFF_TOPK);
  if (tid < 100) topk[b * 100 + tid] = si[tid];
}

// ---------------- mean/std over elites: one wave per (t,b,a) ----------------
__global__ __launch_bounds__(256) void k_meanstd(float* ws) {
  const int g = blockIdx.x * 4 + (threadIdx.x >> 6);  // 0..1151
  const int ln = threadIdx.x & 63;
  const int t = g / 96; const int rem = g - t * 96;
  const int b = rem / 6; const int a = rem - b * 6;
  const int* topk = (const int*)(ws + OFF_TOPK) + b * 100;
  const float* act = ws + OFF_ACT + (size_t)t * NROWS * 8;
  const bool h2 = (ln < 36);
  int c1 = topk[ln];
  float x1 = act[((size_t)b * 1000 + c1) * 8 + a];
  float x2 = 0.f;
  if (h2) { int cc = topk[ln + 64]; x2 = act[((size_t)b * 1000 + cc) * 8 + a]; }
  float s = x1 + x2;
#pragma unroll
  for (int m = 1; m < 64; m <<= 1) s += __shfl_xor(s, m, 64);
  const float mean = s / 100.0f;
  float d = x1 - mean; float qq = d * d;
  if (h2) { float d2 = x2 - mean; qq += d2 * d2; }
#pragma unroll
  for (int m = 1; m < 64; m <<= 1) qq += __shfl_xor(qq, m, 64);
  if (ln == 0) {
    ws[OFF_MEAN + ((size_t)t * 16 + b) * 8 + a] = mean;
    ws[OFF_STD  + ((size_t)t * 16 + b) * 8 + a] = sqrtf(qq / 100.0f);
  }
}

__global__ void k_out(const float* ws, float* out) {
  int i = threadIdx.x;
  if (i < 96) out[i] = ws[OFF_MEAN + (i / 6) * 8 + (i % 6)];
}

extern "C" void kernel_launch(void* const* d_in, const int* in_sizes, int n_in,
                              void* d_out, int out_size, void* d_ws, size_t ws_size,
                              hipStream_t stream) {
  const float* belief = (const float*)d_in[0];
  const float* state  = (const float*)d_in[1];
  const float* Wb  = (const float*)d_in[2];
  const float* Ws_ = (const float*)d_in[3];
  const float* Wa  = (const float*)d_in[4];
  const float* bb  = (const float*)d_in[5];
  const float* Wz  = (const float*)d_in[6];
  const float* bz  = (const float*)d_in[7];
  const float* Wr  = (const float*)d_in[8];
  const float* br  = (const float*)d_in[9];
  float* ws = (float*)d_ws;   // needs ~21.4 MB

  k_prep<<<280, 256, 0, stream>>>(Wb, Ws_, Wa, bb, Wz, bz, Wr, ws);

  for (int it = 0; it < NITERS; ++it) {
    uint32_t f0 = 0u, f1 = (uint32_t)it;
    tf2x32(0u, 42u, f0, f1);
    k_actions<<<4500, 256, 0, stream>>>(f0, f1, ws);
    k_roll<<<500, 256, 0, stream>>>(ws, belief, state, br);
    k_topk<<<16, 1024, 0, stream>>>(ws);
    k_meanstd<<<288, 256, 0, stream>>>(ws);
  }
  k_out<<<1, 128, 0, stream>>>(ws, (float*)d_out);
}